// Round 4
// baseline (1027.835 us; speedup 1.0000x reference)
//
#include <hip/hip_runtime.h>
#include <hip/hip_bf16.h>

// ---------------------------------------------------------------------------
// SolitonInteractionLayer: fused PDE (sine-Gordon + KdV + Heimburg-Jackson,
// RK4, 3 steps) along T, then out = evolved @ W^T + b via bf16 MFMA GEMM.
//
// PDE: causal stencils only (shift pads zeros on the left). Max dependence
// depth = 12 rhs evals * 4 (dxxxx) = 48 -> tile T with left halo 48, no
// cross-block communication. Thread owns 16 contiguous t-points in regs;
// chunk-boundary halo (4 vals) moves via __shfl_up within 32-lane groups
// (32 chunks per d-column -> 512-t tile, 464 interior, 1.125x redundancy).
// Substep loops iterate i DESCENDING: causal stencils read only lower i,
// overwritten later -> safe in-place update.
//
// R4: (a) step-loops NOT unrolled (#pragma unroll 1) — full unroll was
// ~72 KB of code, >> 32 KB I$, throttling issue to ~61% VALUBusy.
// (b) blockIdx.y swizzle pairs the two blocks sharing each 64B x-line /
// 32B out-sector at linear-id distance 72 (== 0 mod 8 -> same XCD).
// ---------------------------------------------------------------------------

typedef __bf16 bf16x8 __attribute__((ext_vector_type(8)));
typedef __bf16 bf16x4 __attribute__((ext_vector_type(4)));
typedef float  floatx4 __attribute__((ext_vector_type(4)));

#define T_DIM 4096
#define D_DIM 1024
#define NP    16      // t-points per thread chunk
#define HALO  48      // 3 chunks
#define NCH   32      // chunks per d-column (one 32-lane shfl group)
#define TINT  (NCH * NP - HALO)   // 464 interior t per block
#define NTT   9       // ceil(4096/464)

__device__ __forceinline__ float sg_rhs(float c, float m1, float m2, float vv) {
  float dxx = fmaf(-2.f, m1, c) + m2;           // u - 2u1 + u2   (C2 = 1)
  return dxx - __sinf(c) - 0.5f * vv;
}
__device__ __forceinline__ float kdv_rhs(float c, float m1, float m2, float m3) {
  float dxu = c - m1;
  float dx3 = fmaf(-3.f, m1, c) + fmaf(3.f, m2, -m3);   // u -3u1 +3u2 -u3
  return fmaf(-6.f * c, dxu, -dx3 - 0.5f * c);
}
__device__ __forceinline__ float hj_rhs(float c, float m1, float m2, float m3,
                                        float m4, float vv) {
  float gi = (fmaf(c, c, c) + 1.f) * (c - m1);          // (1+u+u^2)*dx(u) @ i
  float gm = (fmaf(m1, m1, m1) + 1.f) * (m1 - m2);      //               @ i-1
  float d4 = fmaf(-4.f, m3, fmaf(6.f, m2, fmaf(-4.f, m1, c))) + m4;  // dxxxx
  return (gi - gm) - d4 - 0.5f * vv;
}

// stencil access with register halo (compile-time idx after unroll)
#define AT(F, i) (((i) >= 0) ? F[(i)] : hl[4 + (i)])
// pull neighbor chunk's top-4 values (lane tr-1 within 32-lane group).
// tr==0 receives its own values: contamination propagates <=4 idx per rhs
// eval -> stays strictly left of t0 after all 12 evals (HALO = 48 = 12*4).
#define XCHG(F) do { \
    hl[0] = __shfl_up(F[NP - 4], 1, 32); \
    hl[1] = __shfl_up(F[NP - 3], 1, 32); \
    hl[2] = __shfl_up(F[NP - 2], 1, 32); \
    hl[3] = __shfl_up(F[NP - 1], 1, 32); \
  } while (0)

__global__ __launch_bounds__(256, 4)
void pde_kernel(const float* __restrict__ x, const float* __restrict__ mix,
                __bf16* __restrict__ evout) {
  const int tid  = threadIdx.x;
  const int tr   = tid & 31;       // chunk index within d-column (shfl group)
  const int dcol = tid >> 5;       // 0..7
  // XCD-pairing swizzle: y = q*8 + r (q=0..15, r=0..7) -> d-group r*16+q.
  // Blocks (q,r) and (q+1,r) cover adjacent 8-wide d halves of the same
  // 64B line and sit 72 apart in linear dispatch id (72 % 8 == 0 -> same
  // XCD under round-robin) so L2 serves the second half-line.
  const int yq   = blockIdx.y >> 3;
  const int yr   = blockIdx.y & 7;
  const int d    = (yr * 16 + yq) * 8 + dcol;
  const int b    = blockIdx.z;
  const int t0   = blockIdx.x * TINT;
  const int tb   = t0 - HALO + tr * NP;   // t of reg[0]

  // softmax(solver_mix) per-thread (3 elements)
  float s0 = mix[0], s1 = mix[1], s2 = mix[2];
  float mxv = fmaxf(s0, fmaxf(s1, s2));
  float e0 = __expf(s0 - mxv), e1 = __expf(s1 - mxv), e2 = __expf(s2 - mxv);
  float inv = 1.f / (e0 + e1 + e2);
  float w0 = e0 * inv, w1 = e1 * inv, w2 = e2 * inv;

  const float* xp = x + ((size_t)b * T_DIM) * D_DIM + d;

  float u0[NP], u[NP], v[NP], ut[NP], vt[NP], au[NP], av[NP], ev[NP], hl[4];

  #pragma unroll
  for (int j = 0; j < NP; ++j) {
    int t = tb + j;
    float xv = (t >= 0 && t < T_DIM) ? xp[(size_t)t * D_DIM] : 0.f;
    // fast tanh: 2*tanh(x) = 2 - 4/(e^{2x}+1); clamp avoids inf/inf
    float xc = fminf(fmaxf(xv, -9.f), 9.f);
    float ex = __expf(2.f * xc);
    u0[j] = 2.f - 4.f * __builtin_amdgcn_rcpf(ex + 1.f);
  }

  // ---------------- sine-Gordon (2nd order, dt = 0.05) ----------------
  {
    const float dt = 0.05f, h = 0.025f, w6 = dt * (1.f / 6.f);
    #pragma unroll
    for (int j = 0; j < NP; ++j) { u[j] = u0[j]; v[j] = 0.f; }
    #pragma unroll 1
    for (int s = 0; s < 3; ++s) {
      XCHG(u);
      #pragma unroll
      for (int i = NP - 1; i >= 0; --i) {            // k1
        float k = sg_rhs(u[i], AT(u, i - 1), AT(u, i - 2), v[i]);
        au[i] = v[i]; av[i] = k;
        ut[i] = fmaf(h, v[i], u[i]);
        vt[i] = fmaf(h, k, v[i]);
      }
      XCHG(ut);
      #pragma unroll
      for (int i = NP - 1; i >= 0; --i) {            // k2
        float k = sg_rhs(ut[i], AT(ut, i - 1), AT(ut, i - 2), vt[i]);
        au[i] = fmaf(2.f, vt[i], au[i]); av[i] = fmaf(2.f, k, av[i]);
        float nu = fmaf(h, vt[i], u[i]);             // u + h*k2u (k2u = old vt)
        vt[i] = fmaf(h, k, v[i]);
        ut[i] = nu;
      }
      XCHG(ut);
      #pragma unroll
      for (int i = NP - 1; i >= 0; --i) {            // k3
        float k = sg_rhs(ut[i], AT(ut, i - 1), AT(ut, i - 2), vt[i]);
        au[i] = fmaf(2.f, vt[i], au[i]); av[i] = fmaf(2.f, k, av[i]);
        float nu = fmaf(dt, vt[i], u[i]);
        vt[i] = fmaf(dt, k, v[i]);
        ut[i] = nu;
      }
      XCHG(ut);
      #pragma unroll
      for (int i = NP - 1; i >= 0; --i) {            // k4 + combine
        float k = sg_rhs(ut[i], AT(ut, i - 1), AT(ut, i - 2), vt[i]);
        au[i] += vt[i]; av[i] += k;
        u[i] = fmaf(w6, au[i], u[i]);
        v[i] = fmaf(w6, av[i], v[i]);
      }
    }
    #pragma unroll
    for (int j = 0; j < NP; ++j) ev[j] = w0 * u[j];
  }

  // ---------------- KdV (1st order, dt = 0.025) ----------------
  {
    const float dt = 0.025f, h = 0.0125f, w6 = dt * (1.f / 6.f);
    #pragma unroll
    for (int j = 0; j < NP; ++j) u[j] = u0[j];
    #pragma unroll 1
    for (int s = 0; s < 3; ++s) {
      XCHG(u);
      #pragma unroll
      for (int i = NP - 1; i >= 0; --i) {            // k1
        float k = kdv_rhs(u[i], AT(u, i - 1), AT(u, i - 2), AT(u, i - 3));
        au[i] = k;
        ut[i] = fmaf(h, k, u[i]);
      }
      XCHG(ut);
      #pragma unroll
      for (int i = NP - 1; i >= 0; --i) {            // k2
        float k = kdv_rhs(ut[i], AT(ut, i - 1), AT(ut, i - 2), AT(ut, i - 3));
        au[i] = fmaf(2.f, k, au[i]);
        ut[i] = fmaf(h, k, u[i]);
      }
      XCHG(ut);
      #pragma unroll
      for (int i = NP - 1; i >= 0; --i) {            // k3
        float k = kdv_rhs(ut[i], AT(ut, i - 1), AT(ut, i - 2), AT(ut, i - 3));
        au[i] = fmaf(2.f, k, au[i]);
        ut[i] = fmaf(dt, k, u[i]);
      }
      XCHG(ut);
      #pragma unroll
      for (int i = NP - 1; i >= 0; --i) {            // k4 + combine
        float k = kdv_rhs(ut[i], AT(ut, i - 1), AT(ut, i - 2), AT(ut, i - 3));
        u[i] = fmaf(w6, au[i] + k, u[i]);
      }
    }
    #pragma unroll
    for (int j = 0; j < NP; ++j) ev[j] = fmaf(w1, u[j], ev[j]);
  }

  // ---------------- Heimburg-Jackson (2nd order, dt = 0.025) ----------------
  {
    const float dt = 0.025f, h = 0.0125f, w6 = dt * (1.f / 6.f);
    #pragma unroll
    for (int j = 0; j < NP; ++j) { u[j] = u0[j]; v[j] = 0.f; }
    #pragma unroll 1
    for (int s = 0; s < 3; ++s) {
      XCHG(u);
      #pragma unroll
      for (int i = NP - 1; i >= 0; --i) {            // k1
        float k = hj_rhs(u[i], AT(u, i - 1), AT(u, i - 2), AT(u, i - 3),
                         AT(u, i - 4), v[i]);
        au[i] = v[i]; av[i] = k;
        ut[i] = fmaf(h, v[i], u[i]);
        vt[i] = fmaf(h, k, v[i]);
      }
      XCHG(ut);
      #pragma unroll
      for (int i = NP - 1; i >= 0; --i) {            // k2
        float k = hj_rhs(ut[i], AT(ut, i - 1), AT(ut, i - 2), AT(ut, i - 3),
                         AT(ut, i - 4), vt[i]);
        au[i] = fmaf(2.f, vt[i], au[i]); av[i] = fmaf(2.f, k, av[i]);
        float nu = fmaf(h, vt[i], u[i]);
        vt[i] = fmaf(h, k, v[i]);
        ut[i] = nu;
      }
      XCHG(ut);
      #pragma unroll
      for (int i = NP - 1; i >= 0; --i) {            // k3
        float k = hj_rhs(ut[i], AT(ut, i - 1), AT(ut, i - 2), AT(ut, i - 3),
                         AT(ut, i - 4), vt[i]);
        au[i] = fmaf(2.f, vt[i], au[i]); av[i] = fmaf(2.f, k, av[i]);
        float nu = fmaf(dt, vt[i], u[i]);
        vt[i] = fmaf(dt, k, v[i]);
        ut[i] = nu;
      }
      XCHG(ut);
      #pragma unroll
      for (int i = NP - 1; i >= 0; --i) {            // k4 + combine
        float k = hj_rhs(ut[i], AT(ut, i - 1), AT(ut, i - 2), AT(ut, i - 3),
                         AT(ut, i - 4), vt[i]);
        au[i] += vt[i]; av[i] += k;
        u[i] = fmaf(w6, au[i], u[i]);
        v[i] = fmaf(w6, av[i], v[i]);
      }
    }
    #pragma unroll
    for (int j = 0; j < NP; ++j) ev[j] = fmaf(w2, u[j], ev[j]);
  }

  // store interior chunks (tr >= 3) as bf16 A-matrix [b*T+t][d]
  if (tr >= 3) {
    #pragma unroll
    for (int j = 0; j < NP; ++j) {
      int t = tb + j;
      if (t < T_DIM)
        evout[((size_t)(b * T_DIM + t)) * D_DIM + d] = (__bf16)ev[j];
    }
  }
}

// ---------------------------------------------------------------------------
// W (fp32, [E][D]) -> bf16
// ---------------------------------------------------------------------------
__global__ __launch_bounds__(256)
void convert_w(const float* __restrict__ W, __bf16* __restrict__ Wb) {
  int i = blockIdx.x * 256 + threadIdx.x;   // over D*D/4
  float4 f = ((const float4*)W)[i];
  bf16x4 o = {(__bf16)f.x, (__bf16)f.y, (__bf16)f.z, (__bf16)f.w};
  ((bf16x4*)Wb)[i] = o;
}

// ---------------------------------------------------------------------------
// GEMM: out[m][n] = sum_k A[m][k] * Wb[n][k] + bias[n]
// M=16384, N=1024, K=1024. 128x256 block tile, 4 waves (2x2 of 64x128),
// BK=64, mfma_f32_16x16x32_bf16. Staging via global_load_lds width=16.
// LDS unpadded (load_lds demands contiguous lane order); bank conflicts
// killed by XOR swizzle: 16B granule kc of row r stored at slot kc^(r&7).
// ---------------------------------------------------------------------------
#define GK   1024

__global__ __launch_bounds__(256, 2)
void gemm_kernel(const __bf16* __restrict__ A, const __bf16* __restrict__ Bw,
                 const float* __restrict__ bias, float* __restrict__ out) {
  __shared__ __align__(16) __bf16 As[128 * 64];   // 16 KB
  __shared__ __align__(16) __bf16 Bs[256 * 64];   // 32 KB

  const int tid  = threadIdx.x;
  const int lane = tid & 63;
  const int wid  = tid >> 6;
  const int m0   = blockIdx.x * 128;
  const int n0   = blockIdx.y * 256;
  const int wm   = (wid >> 1) * 64;    // 0 or 64
  const int wn   = (wid & 1) * 128;    // 0 or 128
  const int l15  = lane & 15;
  const int quad = lane >> 4;

  // staging: lane i of a wave covers row (i>>3) within an 8-row block,
  // swizzled granule kc = (i&7) ^ (i>>3); LDS dest = base + lane*16 (HW).
  const int sr  = lane >> 3;                 // 0..7 row within 8-row block
  const int skc = (lane & 7) ^ sr;           // swizzled global granule

  floatx4 acc[4][8] = {};

  for (int kt = 0; kt < GK; kt += 64) {
    __syncthreads();                 // previous iteration's LDS reads done
    #pragma unroll
    for (int p = 0; p < 4; ++p) {    // A: wave w -> rows [w*32, w*32+32)
      int rowblk = wid * 32 + p * 8;
      const __bf16* ga = A + (size_t)(m0 + rowblk + sr) * GK + kt + skc * 8;
      __builtin_amdgcn_global_load_lds((const uint32_t*)ga,
                                       (uint32_t*)&As[rowblk * 64], 16, 0, 0);
    }
    #pragma unroll
    for (int p = 0; p < 8; ++p) {    // B: wave w -> rows [w*64, w*64+64)
      int rowblk = wid * 64 + p * 8;
      const __bf16* gb = Bw + (size_t)(n0 + rowblk + sr) * GK + kt + skc * 8;
      __builtin_amdgcn_global_load_lds((const uint32_t*)gb,
                                       (uint32_t*)&Bs[rowblk * 64], 16, 0, 0);
    }
    __syncthreads();                 // drains vmcnt (load_lds) too
    #pragma unroll
    for (int c = 0; c < 2; ++c) {    // two K=32 chunks
      bf16x8 af[4], bfr[8];
      int kcg = c * 4 + quad;        // global 16B granule within row
      #pragma unroll
      for (int i = 0; i < 4; ++i) {
        int ra = wm + i * 16 + l15;
        af[i] = *(const bf16x8*)(&As[ra * 64 + ((kcg ^ (ra & 7)) * 8)]);
      }
      #pragma unroll
      for (int j = 0; j < 8; ++j) {
        int rb = wn + j * 16 + l15;
        bfr[j] = *(const bf16x8*)(&Bs[rb * 64 + ((kcg ^ (rb & 7)) * 8)]);
      }
      #pragma unroll
      for (int i = 0; i < 4; ++i)
        #pragma unroll
        for (int j = 0; j < 8; ++j)
          acc[i][j] = __builtin_amdgcn_mfma_f32_16x16x32_bf16(
              af[i], bfr[j], acc[i][j], 0, 0, 0);
    }
  }

  // epilogue: D[m=quad*4+r][n=l15] per 16x16 tile; add bias
  #pragma unroll
  for (int j = 0; j < 8; ++j) {
    int n = n0 + wn + j * 16 + l15;
    float bv = bias[n];
    #pragma unroll
    for (int i = 0; i < 4; ++i) {
      int mb = m0 + wm + i * 16 + quad * 4;
      #pragma unroll
      for (int r = 0; r < 4; ++r)
        out[(size_t)(mb + r) * 1024 + n] = acc[i][j][r] + bv;
    }
  }
}

// ---------------------------------------------------------------------------
extern "C" void kernel_launch(void* const* d_in, const int* in_sizes, int n_in,
                              void* d_out, int out_size, void* d_ws, size_t ws_size,
                              hipStream_t stream) {
  const float* x    = (const float*)d_in[0];
  const float* mix  = (const float*)d_in[1];
  const float* W    = (const float*)d_in[2];
  const float* bias = (const float*)d_in[3];
  float* out = (float*)d_out;

  __bf16* ev = (__bf16*)d_ws;                                     // 32 MiB
  __bf16* Wb = (__bf16*)((char*)d_ws + (size_t)32 * 1024 * 1024); // 2 MiB

  convert_w<<<dim3((D_DIM * D_DIM / 4) / 256), 256, 0, stream>>>(W, Wb);
  pde_kernel<<<dim3(NTT, 128, 4), 256, 0, stream>>>(x, mix, ev);
  gemm_kernel<<<dim3(16384 / 128, 1024 / 256), 256, 0, stream>>>(ev, Wb, bias, out);
}

// Round 5
// 315.424 us; speedup vs baseline: 3.2586x; 3.2586x over previous
//
#include <hip/hip_runtime.h>
#include <hip/hip_bf16.h>

// ---------------------------------------------------------------------------
// SolitonInteractionLayer: fused PDE (sine-Gordon + KdV + Heimburg-Jackson,
// RK4, 3 steps) along T, then out = evolved @ W^T + b via bf16 MFMA GEMM.
//
// PDE: causal stencils only (shift pads zeros on the left). Max dependence
// depth = 12 rhs evals * 4 (dxxxx) = 48 -> tile T with left halo 48, no
// cross-block communication. Thread owns 16 contiguous t-points in regs;
// chunk-boundary halo (4 vals) moves via __shfl_up within 32-lane groups
// (32 chunks per d-column -> 512-t tile, 464 interior, 1.125x redundancy).
// Substep loops iterate i DESCENDING: causal stencils read only lower i,
// overwritten later -> safe in-place update.
//
// R5: step-loops #pragma unroll 1 (code ~24 KB, fits I$) but launch_bounds
// back to (256,2): R4's (256,4) capped VGPR at 64 < ~130 live floats ->
// scratch spill (3.2 GB HBM traffic, 930 us). 2 waves/SIMD x ILP=16 points
// is enough issue parallelism; spill avoidance dominates occupancy here.
// ---------------------------------------------------------------------------

typedef __bf16 bf16x8 __attribute__((ext_vector_type(8)));
typedef __bf16 bf16x4 __attribute__((ext_vector_type(4)));
typedef float  floatx4 __attribute__((ext_vector_type(4)));

#define T_DIM 4096
#define D_DIM 1024
#define NP    16      // t-points per thread chunk
#define HALO  48      // 3 chunks
#define NCH   32      // chunks per d-column (one 32-lane shfl group)
#define TINT  (NCH * NP - HALO)   // 464 interior t per block
#define NTT   9       // ceil(4096/464)

__device__ __forceinline__ float sg_rhs(float c, float m1, float m2, float vv) {
  float dxx = fmaf(-2.f, m1, c) + m2;           // u - 2u1 + u2   (C2 = 1)
  return dxx - __sinf(c) - 0.5f * vv;
}
__device__ __forceinline__ float kdv_rhs(float c, float m1, float m2, float m3) {
  float dxu = c - m1;
  float dx3 = fmaf(-3.f, m1, c) + fmaf(3.f, m2, -m3);   // u -3u1 +3u2 -u3
  return fmaf(-6.f * c, dxu, -dx3 - 0.5f * c);
}
__device__ __forceinline__ float hj_rhs(float c, float m1, float m2, float m3,
                                        float m4, float vv) {
  float gi = (fmaf(c, c, c) + 1.f) * (c - m1);          // (1+u+u^2)*dx(u) @ i
  float gm = (fmaf(m1, m1, m1) + 1.f) * (m1 - m2);      //               @ i-1
  float d4 = fmaf(-4.f, m3, fmaf(6.f, m2, fmaf(-4.f, m1, c))) + m4;  // dxxxx
  return (gi - gm) - d4 - 0.5f * vv;
}

// stencil access with register halo (compile-time idx after unroll)
#define AT(F, i) (((i) >= 0) ? F[(i)] : hl[4 + (i)])
// pull neighbor chunk's top-4 values (lane tr-1 within 32-lane group).
// tr==0 receives its own values: contamination propagates <=4 idx per rhs
// eval -> stays strictly left of t0 after all 12 evals (HALO = 48 = 12*4).
#define XCHG(F) do { \
    hl[0] = __shfl_up(F[NP - 4], 1, 32); \
    hl[1] = __shfl_up(F[NP - 3], 1, 32); \
    hl[2] = __shfl_up(F[NP - 2], 1, 32); \
    hl[3] = __shfl_up(F[NP - 1], 1, 32); \
  } while (0)

__global__ __launch_bounds__(256, 2)
void pde_kernel(const float* __restrict__ x, const float* __restrict__ mix,
                __bf16* __restrict__ evout) {
  const int tid  = threadIdx.x;
  const int tr   = tid & 31;       // chunk index within d-column (shfl group)
  const int dcol = tid >> 5;       // 0..7
  // XCD-pairing swizzle: y = q*8 + r (q=0..15, r=0..7) -> d-group r*16+q.
  // Blocks (q,r) and (q+1,r) cover adjacent 8-wide d halves of the same
  // 64B line and sit 72 apart in linear dispatch id (72 % 8 == 0 -> same
  // XCD under round-robin) so L2 serves the second half-line.
  const int yq   = blockIdx.y >> 3;
  const int yr   = blockIdx.y & 7;
  const int d    = (yr * 16 + yq) * 8 + dcol;
  const int b    = blockIdx.z;
  const int t0   = blockIdx.x * TINT;
  const int tb   = t0 - HALO + tr * NP;   // t of reg[0]

  // softmax(solver_mix) per-thread (3 elements)
  float s0 = mix[0], s1 = mix[1], s2 = mix[2];
  float mxv = fmaxf(s0, fmaxf(s1, s2));
  float e0 = __expf(s0 - mxv), e1 = __expf(s1 - mxv), e2 = __expf(s2 - mxv);
  float inv = 1.f / (e0 + e1 + e2);
  float w0 = e0 * inv, w1 = e1 * inv, w2 = e2 * inv;

  const float* xp = x + ((size_t)b * T_DIM) * D_DIM + d;

  float u0[NP], u[NP], v[NP], ut[NP], vt[NP], au[NP], av[NP], ev[NP], hl[4];

  #pragma unroll
  for (int j = 0; j < NP; ++j) {
    int t = tb + j;
    float xv = (t >= 0 && t < T_DIM) ? xp[(size_t)t * D_DIM] : 0.f;
    // fast tanh: 2*tanh(x) = 2 - 4/(e^{2x}+1); clamp avoids inf/inf
    float xc = fminf(fmaxf(xv, -9.f), 9.f);
    float ex = __expf(2.f * xc);
    u0[j] = 2.f - 4.f * __builtin_amdgcn_rcpf(ex + 1.f);
  }

  // ---------------- sine-Gordon (2nd order, dt = 0.05) ----------------
  {
    const float dt = 0.05f, h = 0.025f, w6 = dt * (1.f / 6.f);
    #pragma unroll
    for (int j = 0; j < NP; ++j) { u[j] = u0[j]; v[j] = 0.f; }
    #pragma unroll 1
    for (int s = 0; s < 3; ++s) {
      XCHG(u);
      #pragma unroll
      for (int i = NP - 1; i >= 0; --i) {            // k1
        float k = sg_rhs(u[i], AT(u, i - 1), AT(u, i - 2), v[i]);
        au[i] = v[i]; av[i] = k;
        ut[i] = fmaf(h, v[i], u[i]);
        vt[i] = fmaf(h, k, v[i]);
      }
      XCHG(ut);
      #pragma unroll
      for (int i = NP - 1; i >= 0; --i) {            // k2
        float k = sg_rhs(ut[i], AT(ut, i - 1), AT(ut, i - 2), vt[i]);
        au[i] = fmaf(2.f, vt[i], au[i]); av[i] = fmaf(2.f, k, av[i]);
        float nu = fmaf(h, vt[i], u[i]);             // u + h*k2u (k2u = old vt)
        vt[i] = fmaf(h, k, v[i]);
        ut[i] = nu;
      }
      XCHG(ut);
      #pragma unroll
      for (int i = NP - 1; i >= 0; --i) {            // k3
        float k = sg_rhs(ut[i], AT(ut, i - 1), AT(ut, i - 2), vt[i]);
        au[i] = fmaf(2.f, vt[i], au[i]); av[i] = fmaf(2.f, k, av[i]);
        float nu = fmaf(dt, vt[i], u[i]);
        vt[i] = fmaf(dt, k, v[i]);
        ut[i] = nu;
      }
      XCHG(ut);
      #pragma unroll
      for (int i = NP - 1; i >= 0; --i) {            // k4 + combine
        float k = sg_rhs(ut[i], AT(ut, i - 1), AT(ut, i - 2), vt[i]);
        au[i] += vt[i]; av[i] += k;
        u[i] = fmaf(w6, au[i], u[i]);
        v[i] = fmaf(w6, av[i], v[i]);
      }
    }
    #pragma unroll
    for (int j = 0; j < NP; ++j) ev[j] = w0 * u[j];
  }

  // ---------------- KdV (1st order, dt = 0.025) ----------------
  {
    const float dt = 0.025f, h = 0.0125f, w6 = dt * (1.f / 6.f);
    #pragma unroll
    for (int j = 0; j < NP; ++j) u[j] = u0[j];
    #pragma unroll 1
    for (int s = 0; s < 3; ++s) {
      XCHG(u);
      #pragma unroll
      for (int i = NP - 1; i >= 0; --i) {            // k1
        float k = kdv_rhs(u[i], AT(u, i - 1), AT(u, i - 2), AT(u, i - 3));
        au[i] = k;
        ut[i] = fmaf(h, k, u[i]);
      }
      XCHG(ut);
      #pragma unroll
      for (int i = NP - 1; i >= 0; --i) {            // k2
        float k = kdv_rhs(ut[i], AT(ut, i - 1), AT(ut, i - 2), AT(ut, i - 3));
        au[i] = fmaf(2.f, k, au[i]);
        ut[i] = fmaf(h, k, u[i]);
      }
      XCHG(ut);
      #pragma unroll
      for (int i = NP - 1; i >= 0; --i) {            // k3
        float k = kdv_rhs(ut[i], AT(ut, i - 1), AT(ut, i - 2), AT(ut, i - 3));
        au[i] = fmaf(2.f, k, au[i]);
        ut[i] = fmaf(dt, k, u[i]);
      }
      XCHG(ut);
      #pragma unroll
      for (int i = NP - 1; i >= 0; --i) {            // k4 + combine
        float k = kdv_rhs(ut[i], AT(ut, i - 1), AT(ut, i - 2), AT(ut, i - 3));
        u[i] = fmaf(w6, au[i] + k, u[i]);
      }
    }
    #pragma unroll
    for (int j = 0; j < NP; ++j) ev[j] = fmaf(w1, u[j], ev[j]);
  }

  // ---------------- Heimburg-Jackson (2nd order, dt = 0.025) ----------------
  {
    const float dt = 0.025f, h = 0.0125f, w6 = dt * (1.f / 6.f);
    #pragma unroll
    for (int j = 0; j < NP; ++j) { u[j] = u0[j]; v[j] = 0.f; }
    #pragma unroll 1
    for (int s = 0; s < 3; ++s) {
      XCHG(u);
      #pragma unroll
      for (int i = NP - 1; i >= 0; --i) {            // k1
        float k = hj_rhs(u[i], AT(u, i - 1), AT(u, i - 2), AT(u, i - 3),
                         AT(u, i - 4), v[i]);
        au[i] = v[i]; av[i] = k;
        ut[i] = fmaf(h, v[i], u[i]);
        vt[i] = fmaf(h, k, v[i]);
      }
      XCHG(ut);
      #pragma unroll
      for (int i = NP - 1; i >= 0; --i) {            // k2
        float k = hj_rhs(ut[i], AT(ut, i - 1), AT(ut, i - 2), AT(ut, i - 3),
                         AT(ut, i - 4), vt[i]);
        au[i] = fmaf(2.f, vt[i], au[i]); av[i] = fmaf(2.f, k, av[i]);
        float nu = fmaf(h, vt[i], u[i]);
        vt[i] = fmaf(h, k, v[i]);
        ut[i] = nu;
      }
      XCHG(ut);
      #pragma unroll
      for (int i = NP - 1; i >= 0; --i) {            // k3
        float k = hj_rhs(ut[i], AT(ut, i - 1), AT(ut, i - 2), AT(ut, i - 3),
                         AT(ut, i - 4), vt[i]);
        au[i] = fmaf(2.f, vt[i], au[i]); av[i] = fmaf(2.f, k, av[i]);
        float nu = fmaf(dt, vt[i], u[i]);
        vt[i] = fmaf(dt, k, v[i]);
        ut[i] = nu;
      }
      XCHG(ut);
      #pragma unroll
      for (int i = NP - 1; i >= 0; --i) {            // k4 + combine
        float k = hj_rhs(ut[i], AT(ut, i - 1), AT(ut, i - 2), AT(ut, i - 3),
                         AT(ut, i - 4), vt[i]);
        au[i] += vt[i]; av[i] += k;
        u[i] = fmaf(w6, au[i], u[i]);
        v[i] = fmaf(w6, av[i], v[i]);
      }
    }
    #pragma unroll
    for (int j = 0; j < NP; ++j) ev[j] = fmaf(w2, u[j], ev[j]);
  }

  // store interior chunks (tr >= 3) as bf16 A-matrix [b*T+t][d]
  if (tr >= 3) {
    #pragma unroll
    for (int j = 0; j < NP; ++j) {
      int t = tb + j;
      if (t < T_DIM)
        evout[((size_t)(b * T_DIM + t)) * D_DIM + d] = (__bf16)ev[j];
    }
  }
}

// ---------------------------------------------------------------------------
// W (fp32, [E][D]) -> bf16
// ---------------------------------------------------------------------------
__global__ __launch_bounds__(256)
void convert_w(const float* __restrict__ W, __bf16* __restrict__ Wb) {
  int i = blockIdx.x * 256 + threadIdx.x;   // over D*D/4
  float4 f = ((const float4*)W)[i];
  bf16x4 o = {(__bf16)f.x, (__bf16)f.y, (__bf16)f.z, (__bf16)f.w};
  ((bf16x4*)Wb)[i] = o;
}

// ---------------------------------------------------------------------------
// GEMM: out[m][n] = sum_k A[m][k] * Wb[n][k] + bias[n]
// M=16384, N=1024, K=1024. 128x256 block tile, 4 waves (2x2 of 64x128),
// BK=64, mfma_f32_16x16x32_bf16. Staging via global_load_lds width=16.
// LDS unpadded (load_lds demands contiguous lane order); bank conflicts
// killed by XOR swizzle: 16B granule kc of row r stored at slot kc^(r&7).
// ---------------------------------------------------------------------------
#define GK   1024

__global__ __launch_bounds__(256, 2)
void gemm_kernel(const __bf16* __restrict__ A, const __bf16* __restrict__ Bw,
                 const float* __restrict__ bias, float* __restrict__ out) {
  __shared__ __align__(16) __bf16 As[128 * 64];   // 16 KB
  __shared__ __align__(16) __bf16 Bs[256 * 64];   // 32 KB

  const int tid  = threadIdx.x;
  const int lane = tid & 63;
  const int wid  = tid >> 6;
  const int m0   = blockIdx.x * 128;
  const int n0   = blockIdx.y * 256;
  const int wm   = (wid >> 1) * 64;    // 0 or 64
  const int wn   = (wid & 1) * 128;    // 0 or 128
  const int l15  = lane & 15;
  const int quad = lane >> 4;

  // staging: lane i of a wave covers row (i>>3) within an 8-row block,
  // swizzled granule kc = (i&7) ^ (i>>3); LDS dest = base + lane*16 (HW).
  const int sr  = lane >> 3;                 // 0..7 row within 8-row block
  const int skc = (lane & 7) ^ sr;           // swizzled global granule

  floatx4 acc[4][8] = {};

  for (int kt = 0; kt < GK; kt += 64) {
    __syncthreads();                 // previous iteration's LDS reads done
    #pragma unroll
    for (int p = 0; p < 4; ++p) {    // A: wave w -> rows [w*32, w*32+32)
      int rowblk = wid * 32 + p * 8;
      const __bf16* ga = A + (size_t)(m0 + rowblk + sr) * GK + kt + skc * 8;
      __builtin_amdgcn_global_load_lds((const uint32_t*)ga,
                                       (uint32_t*)&As[rowblk * 64], 16, 0, 0);
    }
    #pragma unroll
    for (int p = 0; p < 8; ++p) {    // B: wave w -> rows [w*64, w*64+64)
      int rowblk = wid * 64 + p * 8;
      const __bf16* gb = Bw + (size_t)(n0 + rowblk + sr) * GK + kt + skc * 8;
      __builtin_amdgcn_global_load_lds((const uint32_t*)gb,
                                       (uint32_t*)&Bs[rowblk * 64], 16, 0, 0);
    }
    __syncthreads();                 // drains vmcnt (load_lds) too
    #pragma unroll
    for (int c = 0; c < 2; ++c) {    // two K=32 chunks
      bf16x8 af[4], bfr[8];
      int kcg = c * 4 + quad;        // global 16B granule within row
      #pragma unroll
      for (int i = 0; i < 4; ++i) {
        int ra = wm + i * 16 + l15;
        af[i] = *(const bf16x8*)(&As[ra * 64 + ((kcg ^ (ra & 7)) * 8)]);
      }
      #pragma unroll
      for (int j = 0; j < 8; ++j) {
        int rb = wn + j * 16 + l15;
        bfr[j] = *(const bf16x8*)(&Bs[rb * 64 + ((kcg ^ (rb & 7)) * 8)]);
      }
      #pragma unroll
      for (int i = 0; i < 4; ++i)
        #pragma unroll
        for (int j = 0; j < 8; ++j)
          acc[i][j] = __builtin_amdgcn_mfma_f32_16x16x32_bf16(
              af[i], bfr[j], acc[i][j], 0, 0, 0);
    }
  }

  // epilogue: D[m=quad*4+r][n=l15] per 16x16 tile; add bias
  #pragma unroll
  for (int j = 0; j < 8; ++j) {
    int n = n0 + wn + j * 16 + l15;
    float bv = bias[n];
    #pragma unroll
    for (int i = 0; i < 4; ++i) {
      int mb = m0 + wm + i * 16 + quad * 4;
      #pragma unroll
      for (int r = 0; r < 4; ++r)
        out[(size_t)(mb + r) * 1024 + n] = acc[i][j][r] + bv;
    }
  }
}

// ---------------------------------------------------------------------------
extern "C" void kernel_launch(void* const* d_in, const int* in_sizes, int n_in,
                              void* d_out, int out_size, void* d_ws, size_t ws_size,
                              hipStream_t stream) {
  const float* x    = (const float*)d_in[0];
  const float* mix  = (const float*)d_in[1];
  const float* W    = (const float*)d_in[2];
  const float* bias = (const float*)d_in[3];
  float* out = (float*)d_out;

  __bf16* ev = (__bf16*)d_ws;                                     // 32 MiB
  __bf16* Wb = (__bf16*)((char*)d_ws + (size_t)32 * 1024 * 1024); // 2 MiB

  convert_w<<<dim3((D_DIM * D_DIM / 4) / 256), 256, 0, stream>>>(W, Wb);
  pde_kernel<<<dim3(NTT, 128, 4), 256, 0, stream>>>(x, mix, ev);
  gemm_kernel<<<dim3(16384 / 128, 1024 / 256), 256, 0, stream>>>(ev, Wb, bias, out);
}